// Round 18
// baseline (461.804 us; speedup 1.0000x reference)
//
#include <hip/hip_runtime.h>
#include <float.h>

// VectorQuantizer: N=262144 rows of D=64 fp32, K=1024 codebook rows.
// out = [x_quantized (N*D f32) | embed_inds (N, written as f32)]
//
// Bit-exact np-fp32 semantics (verified R4): score = fmaf(-2, seq-dot,
// fadd(xnorm, enorm)); pairwise-8 norms; strict < ascending k (first-min).
//
// R18 = R17 (async double-buffered LDS cb tiles; 2 x-rows/thread in named
// float4s) + DUAL-PIPE cb operand: R17 was LDS-return-bound (16 broadcast
// b128/k = 256 B/lane/k -> 437us model ~= 452 measured; broadcast saves
// banks, not delivery). Now d0..31 arrives via s_load_dwordx16 on the
// SCALAR pipe (v_fma takes the SGPR operand) and only d32..63 via LDS
// (68 B/lane/k -> ~116us). VALU (~228us) becomes the sole bound. The
// SGPR-half FMAs run while the ds_reads return; sibling wave hides s_load
// latency. Chain stays d0->63 sequential: operand source != rounding.

typedef __attribute__((address_space(1))) const void gvoid_t;
typedef __attribute__((address_space(3))) void svoid_t;
typedef __attribute__((ext_vector_type(16))) float f32x16;

static constexpr int D_DIM = 64;
static constexpr int K_CB  = 1024;
static constexpr int TPB   = 256;           // 4 waves
static constexpr int RPB   = 512;           // 2 rows/thread -> grid 512
static constexpr int KTILE = 128;           // cb rows per LDS tile
static constexpr int NKT   = K_CB / KTILE;  // 8 tiles
static constexpr int HALF  = 32;            // floats per row in LDS (d32..63)

// numpy pairwise-8 sum of squares of 64 values held as 16 float4s.
#define NP_INIT(c0, c1)                                                     \
    float ax = __fmul_rn(c0.x, c0.x), ay = __fmul_rn(c0.y, c0.y),           \
          az = __fmul_rn(c0.z, c0.z), aw = __fmul_rn(c0.w, c0.w);           \
    float bx = __fmul_rn(c1.x, c1.x), by = __fmul_rn(c1.y, c1.y),           \
          bz = __fmul_rn(c1.z, c1.z), bw = __fmul_rn(c1.w, c1.w);
#define NP_ACC(ce, co)                                                      \
    ax = __fadd_rn(ax, __fmul_rn(ce.x, ce.x));                              \
    ay = __fadd_rn(ay, __fmul_rn(ce.y, ce.y));                              \
    az = __fadd_rn(az, __fmul_rn(ce.z, ce.z));                              \
    aw = __fadd_rn(aw, __fmul_rn(ce.w, ce.w));                              \
    bx = __fadd_rn(bx, __fmul_rn(co.x, co.x));                              \
    by = __fadd_rn(by, __fmul_rn(co.y, co.y));                              \
    bz = __fadd_rn(bz, __fmul_rn(co.z, co.z));                              \
    bw = __fadd_rn(bw, __fmul_rn(co.w, co.w));
#define NP_TREE()                                                           \
    __fadd_rn(__fadd_rn(__fadd_rn(ax, ay), __fadd_rn(az, aw)),              \
              __fadd_rn(__fadd_rn(bx, by), __fadd_rn(bz, bw)))

__device__ __forceinline__ float np_pair_sq16(
        float4 c0, float4 c1, float4 c2, float4 c3,
        float4 c4, float4 c5, float4 c6, float4 c7,
        float4 c8, float4 c9, float4 c10, float4 c11,
        float4 c12, float4 c13, float4 c14, float4 c15) {
    NP_INIT(c0, c1)
    NP_ACC(c2, c3)  NP_ACC(c4, c5)  NP_ACC(c6, c7)
    NP_ACC(c8, c9)  NP_ACC(c10, c11) NP_ACC(c12, c13) NP_ACC(c14, c15)
    return NP_TREE();
}

// 4 chain steps for both rows; cb scalar sv[base..base+3], x float4s xa/xb.
#define FMA4S(sv, base, xa, xb)                                             \
    dA = __fmaf_rn(sv[base + 0], xa.x, dA);                                 \
    dB = __fmaf_rn(sv[base + 0], xb.x, dB);                                 \
    dA = __fmaf_rn(sv[base + 1], xa.y, dA);                                 \
    dB = __fmaf_rn(sv[base + 1], xb.y, dB);                                 \
    dA = __fmaf_rn(sv[base + 2], xa.z, dA);                                 \
    dB = __fmaf_rn(sv[base + 2], xb.z, dB);                                 \
    dA = __fmaf_rn(sv[base + 3], xa.w, dA);                                 \
    dB = __fmaf_rn(sv[base + 3], xb.w, dB);

// 4 chain steps for both rows; cb float4 from LDS, x float4s xa/xb.
#define FMA4L(q, xa, xb)                                                    \
    dA = __fmaf_rn(q.x, xa.x, dA); dB = __fmaf_rn(q.x, xb.x, dB);           \
    dA = __fmaf_rn(q.y, xa.y, dA); dB = __fmaf_rn(q.y, xb.y, dB);           \
    dA = __fmaf_rn(q.z, xa.z, dA); dB = __fmaf_rn(q.z, xb.z, dB);           \
    dA = __fmaf_rn(q.w, xa.w, dA); dB = __fmaf_rn(q.w, xb.w, dB);

__global__ void __launch_bounds__(TPB)
__attribute__((amdgpu_waves_per_eu(2, 2)))
vq_kernel(
        const float* __restrict__ x, const float* __restrict__ cb,
        float* __restrict__ out_q, float* __restrict__ out_idx) {
    __shared__ float cbt[2][KTILE * HALF];   // 2 x 16 KB: d32..63 halves
    __shared__ float es[K_CB];               // 4 KB
    __shared__ int   bks[RPB];               // 2 KB    total ~38 KB

    const int tid = threadIdx.x;
    const size_t row0 = (size_t)blockIdx.x * RPB;
    const size_t rowA = row0 + tid;
    const size_t rowB = row0 + TPB + tid;
    const float4* cb4 = reinterpret_cast<const float4*>(cb);

    // ---- prologue: async-stage tile 0 second-halves (overlaps A/B) ----
#pragma unroll
    for (int j = 0; j < 4; ++j) {
        const int f = tid + TPB * j;          // 0..1023 float4 slots
        const int r = f >> 3, c = f & 7;      // row, chunk within half
        __builtin_amdgcn_global_load_lds(
            (gvoid_t*)(cb + (size_t)r * D_DIM + HALF + c * 4),
            (svoid_t*)(&cbt[0][f * 4]), 16, 0, 0);
    }

    // ---- phase A: block-local e-norms (numpy pairwise order) ----
#pragma unroll
    for (int j = 0; j < K_CB / TPB; ++j) {
        const int k = tid + TPB * j;
        const float4* cr = cb4 + (size_t)k * 16;
        float4 c0 = cr[0],  c1 = cr[1],  c2 = cr[2],  c3 = cr[3],
               c4 = cr[4],  c5 = cr[5],  c6 = cr[6],  c7 = cr[7],
               c8 = cr[8],  c9 = cr[9],  c10 = cr[10], c11 = cr[11],
               c12 = cr[12], c13 = cr[13], c14 = cr[14], c15 = cr[15];
        es[k] = np_pair_sq16(c0, c1, c2, c3, c4, c5, c6, c7,
                             c8, c9, c10, c11, c12, c13, c14, c15);
    }

    // ---- phase B: my 2 rows in 32 NAMED float4 registers; x_norms ----
    const float4* ga = reinterpret_cast<const float4*>(x + rowA * D_DIM);
    float4 a0 = ga[0],  a1 = ga[1],  a2 = ga[2],  a3 = ga[3],
           a4 = ga[4],  a5 = ga[5],  a6 = ga[6],  a7 = ga[7],
           a8 = ga[8],  a9 = ga[9],  a10 = ga[10], a11 = ga[11],
           a12 = ga[12], a13 = ga[13], a14 = ga[14], a15 = ga[15];
    const float xnA = np_pair_sq16(a0, a1, a2, a3, a4, a5, a6, a7,
                                   a8, a9, a10, a11, a12, a13, a14, a15);
    const float4* gb = reinterpret_cast<const float4*>(x + rowB * D_DIM);
    float4 b0 = gb[0],  b1 = gb[1],  b2 = gb[2],  b3 = gb[3],
           b4 = gb[4],  b5 = gb[5],  b6 = gb[6],  b7 = gb[7],
           b8 = gb[8],  b9 = gb[9],  b10 = gb[10], b11 = gb[11],
           b12 = gb[12], b13 = gb[13], b14 = gb[14], b15 = gb[15];
    const float xnB = np_pair_sq16(b0, b1, b2, b3, b4, b5, b6, b7,
                                   b8, b9, b10, b11, b12, b13, b14, b15);

    asm volatile("s_waitcnt vmcnt(0)" ::: "memory");   // tile 0 landed
    __syncthreads();                                   // es + tile 0 visible

    // ---- phase C: k-scan; cb d0..31 via scalar pipe, d32..63 via LDS ----
    float bestA = FLT_MAX, bestB = FLT_MAX;
    int kA = 0, kB = 0;
    unsigned long long cbp = (unsigned long long)cb;   // row k base (bytes)
    for (int t = 0; t < NKT; ++t) {
        if (t + 1 < NKT) {                   // async stage of tile t+1 halves
            const float* src = cb + (size_t)(t + 1) * KTILE * D_DIM;
            float* dst = cbt[(t + 1) & 1];
#pragma unroll
            for (int j = 0; j < 4; ++j) {
                const int f = tid + TPB * j;
                const int r = f >> 3, c = f & 7;
                __builtin_amdgcn_global_load_lds(
                    (gvoid_t*)(src + (size_t)r * D_DIM + HALF + c * 4),
                    (svoid_t*)(&dst[f * 4]), 16, 0, 0);
            }
        }

        const float* xtc = cbt[t & 1];
#pragma unroll 2
        for (int kk = 0; kk < KTILE; ++kk) {
            const int k = t * KTILE + kk;
            // d0..31 -> SGPRs (scalar pipe; wave-uniform row address)
            f32x16 s0_, s1_;
            asm volatile(
                "s_load_dwordx16 %0, %2, 0x0\n\t"
                "s_load_dwordx16 %1, %2, 0x40\n\t"
                "s_waitcnt lgkmcnt(0)"
                : "=s"(s0_), "=s"(s1_)
                : "s"(cbp) : "memory");
            // d32..63 -> LDS broadcast reads (issue now, consumed later)
            const float4* cr = reinterpret_cast<const float4*>(&xtc[kk * HALF]);
            const float4 q0 = cr[0], q1 = cr[1], q2 = cr[2], q3 = cr[3],
                         q4 = cr[4], q5 = cr[5], q6 = cr[6], q7 = cr[7];
            const float en = es[k];

            float dA = 0.f, dB = 0.f;
            // d0..15 (SGPR set 0), d16..31 (SGPR set 1) — chain ascending.
            FMA4S(s0_, 0,  a0, b0)  FMA4S(s0_, 4,  a1, b1)
            FMA4S(s0_, 8,  a2, b2)  FMA4S(s0_, 12, a3, b3)
            FMA4S(s1_, 0,  a4, b4)  FMA4S(s1_, 4,  a5, b5)
            FMA4S(s1_, 8,  a6, b6)  FMA4S(s1_, 12, a7, b7)
            // d32..63 from LDS (landed during the 256-cyc SGPR half).
            FMA4L(q0, a8,  b8)   FMA4L(q1, a9,  b9)
            FMA4L(q2, a10, b10)  FMA4L(q3, a11, b11)
            FMA4L(q4, a12, b12)  FMA4L(q5, a13, b13)
            FMA4L(q6, a14, b14)  FMA4L(q7, a15, b15)

            const float sA = __fmaf_rn(-2.f, dA, __fadd_rn(xnA, en));
            const float sB = __fmaf_rn(-2.f, dB, __fadd_rn(xnB, en));
            if (sA < bestA) { bestA = sA; kA = k; }   // strict < = first-min
            if (sB < bestB) { bestB = sB; kB = k; }
            cbp += 4ull * D_DIM;
        }

        asm volatile("s_waitcnt vmcnt(0)" ::: "memory");  // next tile landed
        __syncthreads();
    }

    bks[tid]       = kA;
    bks[TPB + tid] = kB;
    __syncthreads();

    // ---- phase D: coalesced gather-write of x_quantized (512 rows) ----
    float4* oq = reinterpret_cast<float4*>(out_q + row0 * D_DIM);
#pragma unroll
    for (int j = 0; j < RPB * 16 / TPB; ++j) {
        const int f = tid + TPB * j;     // 0..8191
        const int r = f >> 4, c = f & 15;
        oq[f] = cb4[(size_t)bks[r] * 16 + c];
    }
    out_idx[rowA] = (float)kA;
    out_idx[rowB] = (float)kB;
}

extern "C" void kernel_launch(void* const* d_in, const int* in_sizes, int n_in,
                              void* d_out, int out_size, void* d_ws, size_t ws_size,
                              hipStream_t stream) {
    const float* x  = (const float*)d_in[0];
    const float* cb = (const float*)d_in[1];
    const int n_rows = in_sizes[0] / D_DIM;     // 262144

    float* out_q   = (float*)d_out;
    float* out_idx = out_q + (size_t)n_rows * D_DIM;

    vq_kernel<<<n_rows / RPB, TPB, 0, stream>>>(x, cb, out_q, out_idx);
}